// Round 13
// baseline (353.995 us; speedup 1.0000x reference)
//
#include <hip/hip_runtime.h>
#include <hip/hip_bf16.h>

#define BB 32
#define SS 256
#define DD 128
#define GG 128
#define NG 512   // 4*(H/2) gate columns per direction
#define LL 32
#define LOG2E 1.4426950408889634f

typedef unsigned short u16;
typedef __attribute__((ext_vector_type(8))) short short8;
typedef __attribute__((ext_vector_type(4))) float f32x4;

__device__ __forceinline__ float bf2f(u16 u){ return __uint_as_float(((unsigned)u)<<16); }
__device__ __forceinline__ u16 f2bf(float f){
    unsigned x = __float_as_uint(f);
    unsigned r = x + 0x7fffu + ((x>>16)&1u);
    return (u16)(r>>16);
}
__device__ __forceinline__ float tanh_f(float x){ float e=__expf(2.0f*x); return 1.0f - 2.0f/(e+1.0f); }

__device__ __forceinline__ float exp2_f(float x){
#if __has_builtin(__builtin_amdgcn_exp2f)
    return __builtin_amdgcn_exp2f(x);
#elif __has_builtin(__builtin_amdgcn_expf)
    return __builtin_amdgcn_expf(x);
#else
    return __expf(x * 0.6931471805599453f);
#endif
}
__device__ __forceinline__ float rcp_f(float x){
#if __has_builtin(__builtin_amdgcn_rcpf)
    return __builtin_amdgcn_rcpf(x);
#else
    return 1.0f / x;
#endif
}

// ---------------- kprep: flat job table (exact block ranges) ----------------
// type 0: can[p0+i] = f32(src[i])
// type 1: WcatT[(p0 + c)*128 + k] = bf16(src[k*p1 + c])            (plain W^T)
// type 2: (p0? memWT : tagWT)[(i&31)*256 + (i>>5)] = bf16(...)
// type 3: label row-norm -> WcatT cols 1152..1183 (+ zero pad)
// type 4: gate W^T with q-permute
// type 5: token gather+norm -> weC(bf16), invn
#define NJOBS 22
struct PJobs { const void* src[NJOBS]; int n[NJOBS]; int p0[NJOBS]; int p1[NJOBS];
               int type[NJOBS]; int blk0[NJOBS]; };

__global__ void kprep(PJobs jb, const void* __restrict__ wemb, const int* __restrict__ wid,
                      int* __restrict__ flags, float* __restrict__ can,
                      u16* __restrict__ WcatT, u16* __restrict__ tagWT, u16* __restrict__ memWT,
                      u16* __restrict__ weC, float* __restrict__ invn){
    int t = threadIdx.x;
    __shared__ int cw[4];
    __shared__ int sflag;
    {
        u16 v = ((const u16*)wemb)[2*t];
        int e = (v>>7)&0xFF;
        int c = (e>=0x90)?1:0;
        #pragma unroll
        for (int mk=32; mk>0; mk>>=1) c += __shfl_xor(c, mk);
        if ((t&63)==0) cw[t>>6] = c;
        __syncthreads();
        if (t==0) sflag = (cw[0]+cw[1]+cw[2]+cw[3] >= 32) ? 1 : 0;
        __syncthreads();
    }
    int f = sflag;
    if (blockIdx.x==0 && t==0) flags[0] = f;

    int bx = blockIdx.x;
    int id = 0;
    #pragma unroll
    for (int jj=1; jj<NJOBS; jj++) if (bx >= jb.blk0[jj]) id = jj;
    int i = (bx - jb.blk0[id])*256 + t;
    if (i >= jb.n[id]) return;
    const void* src = jb.src[id];
    int p0 = jb.p0[id];
    int ty = jb.type[id];
    if (ty == 0){
        float v = f ? ((const float*)src)[i] : bf2f(((const u16*)src)[i]);
        can[p0 + i] = v;
    } else if (ty == 1){
        int c = i>>7, k = i&127;
        float v = f ? ((const float*)src)[k*jb.p1[id] + c] : bf2f(((const u16*)src)[k*jb.p1[id] + c]);
        WcatT[(size_t)(p0 + c)*128 + k] = f2bf(v);
    } else if (ty == 2){
        int l = i&31, k = i>>5;
        float v = f ? ((const float*)src)[k*32 + l] : bf2f(((const u16*)src)[k*32 + l]);
        (p0 ? memWT : tagWT)[l*256 + k] = f2bf(v);
    } else if (ty == 3){
        int row = i>>7, col = i&127;
        float v = f ? ((const float*)src)[i] : bf2f(((const u16*)src)[i]);
        float sq = v*v;
        #pragma unroll
        for (int mk=32; mk>0; mk>>=1) sq += __shfl_xor(sq, mk);
        __shared__ float r4[4];
        if ((t&63)==0) r4[t>>6] = sq;
        __syncthreads();
        int half = t>>7;
        float tot = r4[half*2] + r4[half*2+1];
        float inv = 1.0f/(sqrtf(tot) + 1e-8f);
        WcatT[(size_t)(1152+row)*128 + col] = f2bf(v*inv);
        WcatT[(size_t)(1184+row)*128 + col] = 0;   // pad cols
    } else if (ty == 4){
        int c = i>>7, k = i&127;
        float v = f ? ((const float*)src)[k*512 + c] : bf2f(((const u16*)src)[k*512 + c]);
        int q = c>>7, rem = c&127, w5 = rem>>4, li = rem&15;
        WcatT[(size_t)(p0 + w5*64 + q*16 + li)*128 + k] = f2bf(v);
    } else {
        // type 5: token gather + norm (8 tokens per block, 32 lanes each)
        int tok = i>>5, lane = i&31;
        int idx = wid[tok];
        float v0,v1,v2,v3;
        if (f){
            f32x4 u = *(const f32x4*)((const float*)wemb + (size_t)idx*DD + lane*4);
            v0=u[0]; v1=u[1]; v2=u[2]; v3=u[3];
        } else {
            ushort4 u = *(const ushort4*)((const u16*)wemb + (size_t)idx*DD + lane*4);
            v0=bf2f(u.x); v1=bf2f(u.y); v2=bf2f(u.z); v3=bf2f(u.w);
        }
        int b = tok>>8, s = tok&255;
        int m = s*BB + b;
        ushort4 wv;
        wv.x=f2bf(v0); wv.y=f2bf(v1); wv.z=f2bf(v2); wv.w=f2bf(v3);
        *(ushort4*)&weC[(size_t)m*DD + lane*4] = wv;
        float sq = v0*v0 + v1*v1 + v2*v2 + v3*v3;
        #pragma unroll
        for (int mk=16; mk>0; mk>>=1) sq += __shfl_xor(sq, mk);
        if (lane==0) invn[m] = 1.0f/(sqrtf(sq) + 1e-8f);
    }
}

// ---------------- kgemm: [gpre4(f32) | sent_h | lab_e] = weC @ WcatT, MFMA ----------------
// nb<16: (dir = nb>>3, w5 = nb&7), q-permuted cols -> f32x4-coalesced gpre4 stores.
__global__ __launch_bounds__(256) void kgemm(const u16* __restrict__ weC,
                      const u16* __restrict__ WcatT,
                      const float* __restrict__ invn, const float* __restrict__ sentBc,
                      float* __restrict__ gpre4, float* __restrict__ sent_h,
                      float* __restrict__ lab_e){
    int mt = blockIdx.x;            // 0..127
    int nb = blockIdx.y;            // 0..18
    int t = threadIdx.x;
    int w4 = t>>6, l = t&63, li = l&15, lg = l>>4;
    int mbase = mt*64 + w4*16;
    int n0 = nb*64;
    short8 af[4];
    #pragma unroll
    for (int ks=0;ks<4;ks++)
        af[ks] = *(const short8*)&weC[(size_t)(mbase + li)*128 + ks*32 + lg*8];
    f32x4 acc[4];
    #pragma unroll
    for (int nt=0;nt<4;nt++){
        short8 bf[4];
        #pragma unroll
        for (int ks=0;ks<4;ks++)
            bf[ks] = *(const short8*)&WcatT[(size_t)(n0 + nt*16 + li)*128 + ks*32 + lg*8];
        f32x4 a; a[0]=0.f; a[1]=0.f; a[2]=0.f; a[3]=0.f;
        #pragma unroll
        for (int ks=0;ks<4;ks++)
            a = __builtin_amdgcn_mfma_f32_16x16x32_bf16(af[ks], bf[ks], a, 0,0,0);
        acc[nt] = a;
    }
    if (nb < 16){
        int dir = nb>>3, w5 = nb&7;
        int s = mt*2 + (w4>>1);
        int bg = (w4&1)*4 + lg;
        float* gp = gpre4 + ((((size_t)(dir*8+bg)*256 + s)*8 + w5)*256);
        #pragma unroll
        for (int r=0;r<4;r++){
            f32x4 v;
            v[0] = acc[0][r]*LOG2E;
            v[1] = acc[1][r]*LOG2E;
            v[2] = acc[2][r]*(2.0f*LOG2E);
            v[3] = acc[3][r]*LOG2E;
            *(f32x4*)&gp[(r*16 + li)*4] = v;
        }
    } else {
        int mrow = mbase + lg*4;
        #pragma unroll
        for (int nt=0;nt<4;nt++){
            int n = n0 + nt*16 + li;
            if (n < 1152){
                int c = n - 1024;
                float bb = sentBc[c];
                #pragma unroll
                for (int r=0;r<4;r++){
                    int m = mrow + r;
                    int b = m&31, s = m>>5;
                    sent_h[((size_t)(b*256+s))*128 + c] = tanh_f(acc[nt][r] + bb);
                }
            } else if (n < 1184){
                int c = n - 1152;
                #pragma unroll
                for (int r=0;r<4;r++){
                    int m = mrow + r;
                    int b = m&31, s = m>>5;
                    lab_e[((size_t)(b*256+s))*32 + c] = acc[nt][r] * invn[m];
                }
            }
        }
    }
}

// ---------------- k23f: conv+relu+max+exp -> attention -> sent_rep -> cpart ----------------
// One block per batch (32 x 256 thr). All state staged through LDS; no per-thread
// arrays (avoids the R5 spill trap). Conv runs per 32-s stripe with re-staged le tile.
__global__ __launch_bounds__(256) void k23f(const float* __restrict__ lab_e,
                        const float* __restrict__ convWc, const float* __restrict__ convBc,
                        const float* __restrict__ sent_h,
                        const int* __restrict__ lens,
                        const float* __restrict__ Wfc, const float* __restrict__ Wbc,
                        const float* __restrict__ bfc, const float* __restrict__ bbc,
                        float* __restrict__ cpart){
    int b = blockIdx.x, t = threadIdx.x;
    __shared__ float le_s[34*33];
    __shared__ float wle[LL*LL*3];
    __shared__ float wb[LL];
    __shared__ float es_all[SS];
    __shared__ float red[2][GG];
    __shared__ float srs[GG];
    __shared__ float ew[4];
    for (int i=t; i<LL*LL*3; i+=256) wle[i] = convWc[i];
    if (t < LL) wb[t] = convBc[t];
    int lenb = lens[b];
    int sl = t>>3, oq = t&7;
    for (int st=0; st<8; st++){
        int s0 = st*32;
        __syncthreads();   // protect le_s from previous stripe's readers
        for (int i=t; i<34*32; i+=256){
            int row = i>>5, col = i&31;
            int sg = s0 - 1 + row;
            le_s[row*33 + col] = (sg>=0 && sg<SS) ? lab_e[(size_t)b*SS*LL + sg*LL + col] : 0.f;
        }
        __syncthreads();
        int s = s0 + sl;
        float lm = 0.f;   // relu >= 0
        #pragma unroll
        for (int op=0; op<4; op++){
            int o = oq*4 + op;
            float a0 = wb[o], a1 = 0.f, a2 = 0.f;
            #pragma unroll
            for (int i=0;i<LL;i++){
                a0 = fmaf(le_s[(sl+0)*33+i], wle[o*96 + i*3    ], a0);
                a1 = fmaf(le_s[(sl+1)*33+i], wle[o*96 + i*3 + 1], a1);
                a2 = fmaf(le_s[(sl+2)*33+i], wle[o*96 + i*3 + 2], a2);
            }
            lm = fmaxf(lm, fmaxf(a0+a1+a2, 0.f));
        }
        #pragma unroll
        for (int mk=1; mk<8; mk<<=1) lm = fmaxf(lm, __shfl_xor(lm, mk));
        if (oq == 0) es_all[s] = (s < lenb) ? __expf(lm) : 0.f;
    }
    __syncthreads();
    // e-sum (wave reduce + 4-wave combine)
    {
        float e = es_all[t];
        #pragma unroll
        for (int mk=32; mk>0; mk>>=1) e += __shfl_xor(e, mk);
        if ((t&63)==0) ew[t>>6] = e;
    }
    __syncthreads();
    float inv = 1.0f/(ew[0]+ew[1]+ew[2]+ew[3]);
    // attention: 2-way s-split over 256 threads
    int col = t&127, sh = t>>7;
    {
        float a0 = 0.f, a1 = 0.f;
        int sb = sh*128;
        for (int s2=sb; s2<sb+128; s2+=2){
            a0 = fmaf(es_all[s2],   sent_h[((size_t)b*SS + s2)*GG + col], a0);
            a1 = fmaf(es_all[s2+1], sent_h[((size_t)b*SS + s2+1)*GG + col], a1);
        }
        red[sh][col] = a0+a1;
    }
    __syncthreads();
    if (t < GG) srs[t] = (red[0][t]+red[1][t])*inv;
    __syncthreads();
    // cpart matvec (coalesced W reads: n consecutive across lanes)
    #pragma unroll
    for (int chunk=0; chunk<4; chunk++){
        int ng = chunk*256 + t;          // 0..1023
        int dir = ng>>9, n = ng&511;
        const float* W = dir ? Wbc : Wfc;
        float c0 = (dir ? bbc : bfc)[n], c1 = 0.f;
        for (int g=0; g<GG; g+=2){
            c0 = fmaf(srs[g],   W[(size_t)(DD+g)*NG + n], c0);
            c1 = fmaf(srs[g+1], W[(size_t)(DD+g+1)*NG + n], c1);
        }
        cpart[((size_t)dir*NG + n)*BB + b] = c0+c1;
    }
}

// ---------------- K5: bidir LSTM, 16 wgs, 1 cell/lane, predicated A-read (frozen R10 form) ----------------
__global__ __launch_bounds__(512) void k5_lstm(const float* __restrict__ gpre4,
                       const float* __restrict__ Ufc, const float* __restrict__ Ubc,
                       const float* __restrict__ cpart,
                       const int* __restrict__ lens, float* __restrict__ feat){
    int dir = blockIdx.x>>3, bg = blockIdx.x&7;
    int t = threadIdx.x;
    int w = t>>6, l = t&63, lg = l>>4, li = l&15;
    int j = w*16 + li;                         // hidden column 0..127
    int b = bg*4 + lg;                         // this lane's batch
    const float* Uc = dir ? Ubc : Ufc;

    short8 bfr[4][4];
    #pragma unroll
    for (int q=0;q<4;q++){
        float sc = (q==2) ? 2.0f*LOG2E : LOG2E;
        #pragma unroll
        for (int ks=0;ks<4;ks++){
            int n = q*128 + j;
            short8 v;
            #pragma unroll
            for (int jj=0;jj<8;jj++)
                v[jj] = (short)f2bf(Uc[(size_t)(ks*32 + lg*8 + jj)*NG + n] * sc);
            bfr[q][ks] = v;
        }
    }
    float cpr[4];
    #pragma unroll
    for (int q=0;q<4;q++)
        cpr[q] = cpart[((size_t)(dir*NG + q*128 + j))*BB + b] * ((q==2) ? 2.0f*LOG2E : LOG2E);
    int len1 = lens[b];

    __shared__ u16 Hhi[2][16*128];   // XOR-swizzled, double-buffered
    for (int i=t; i<2*2048; i+=512) ((u16*)Hhi)[i] = 0;

    bool rdp = ((li & 3) == 0);      // only 16 lanes/wave read the A tile
    int roff[4];
    #pragma unroll
    for (int ks=0;ks<4;ks++)
        roff[ks] = (li*256 + ((ks*64 + lg*16) ^ ((li&7)<<4))) >> 1;
    int woff;
    { int row = lg*4; woff = (row*256 + ((2*j) ^ ((row&7)<<4))) >> 1; }

    short8 ah[4];
    #pragma unroll
    for (int ks=0;ks<4;ks++){
        #pragma unroll
        for (int jj=0;jj<8;jj++) ah[ks][jj] = 0;
    }
    f32x4 acv[4];
    #pragma unroll
    for (int q=0;q<4;q++){ acv[q][0]=0.f; acv[q][1]=0.f; acv[q][2]=0.f; acv[q][3]=0.f; }

    float c = 0.f, h = 0.f;
    int sgn = dir ? -1 : 1;
    int s0 = dir ? (SS-1) : 0;
    const float* gl = gpre4 + ((size_t)(dir*8 + bg)*256 + s0)*2048 + w*256 + l*4;
    ptrdiff_t gstep = (ptrdiff_t)sgn * 2048;

    f32x4 gA = *(const f32x4*)gl;
    f32x4 gB = *(const f32x4*)(gl + gstep);
    const float* glp = gl + 2*gstep;

    float* fb = feat + ((size_t)b*SS + s0)*256 + dir*128 + j;
    ptrdiff_t fstep = (ptrdiff_t)sgn * 256;

    int s = s0;
    __syncthreads();

#define K5_STEP(P, G)                                                          \
    {                                                                          \
        if (rdp){                                                              \
            ah[0] = *(const short8*)&Hhi[P][roff[0]];                          \
            ah[1] = *(const short8*)&Hhi[P][roff[1]];                          \
            ah[2] = *(const short8*)&Hhi[P][roff[2]];                          \
            ah[3] = *(const short8*)&Hhi[P][roff[3]];                          \
        }                                                                      \
        acv[0][0] = G[0]+cpr[0];                                               \
        acv[1][0] = G[1]+cpr[1];                                               \
        acv[2][0] = G[2]+cpr[2];                                               \
        acv[3][0] = G[3]+cpr[3];                                               \
        if (tt2 + 2 < SS){ G = *(const f32x4*)glp; glp += gstep; }             \
        _Pragma("unroll")                                                      \
        for (int ks=0;ks<4;ks++){                                              \
            _Pragma("unroll")                                                  \
            for (int q=0;q<4;q++)                                              \
                acv[q] = __builtin_amdgcn_mfma_f32_16x16x32_bf16(ah[ks], bfr[q][ks], acv[q], 0,0,0); \
        }                                                                      \
        float si = rcp_f(1.0f + exp2_f(-acv[0][0]));                           \
        float sf = rcp_f(1.0f + exp2_f(-acv[1][0]));                           \
        float tg = 1.0f - 2.0f*rcp_f(exp2_f(acv[2][0]) + 1.0f);                \
        float so = rcp_f(1.0f + exp2_f(-acv[3][0]));                           \
        float cn = sf*c + si*tg;                                               \
        float th = 1.0f - 2.0f*rcp_f(exp2_f(cn*(2.0f*LOG2E)) + 1.0f);          \
        float hn = so*th;                                                      \
        if (s < 128){ c = cn; h = hn; fb[0] = hn; }                            \
        else { bool mm = (s < len1); c = mm?cn:c; h = mm?hn:h; fb[0] = mm?hn:0.f; } \
        Hhi[P^1][woff] = f2bf(h);                                              \
        asm volatile("s_waitcnt lgkmcnt(0)" ::: "memory");                     \
        __builtin_amdgcn_sched_barrier(0);                                     \
        __builtin_amdgcn_s_barrier();                                          \
        __builtin_amdgcn_sched_barrier(0);                                     \
        s += sgn; fb += fstep;                                                 \
    }

    for (int tt=0; tt<SS; tt+=2){
        { int tt2 = tt;   K5_STEP(0, gA) }
        { int tt2 = tt+1; K5_STEP(1, gB) }
    }
#undef K5_STEP
}

// ---------------- k6: tag/mem projections + blend (LDS-staged, vectorized) ----------------
__global__ __launch_bounds__(256) void k6_final(const float* __restrict__ feat,
                         const int* __restrict__ wid,
                         const int* __restrict__ lens,
                         const u16* __restrict__ tagWT, const float* __restrict__ tagBc,
                         const u16* __restrict__ memWT, const float* __restrict__ memBc,
                         const void* __restrict__ bank, const int* __restrict__ flags,
                         void* __restrict__ out){
    int t = threadIdx.x;
    int tl = t>>5, lcol = t&31;
    int tok0 = blockIdx.x*8;
    __shared__ float fr_s[8][256];
    __shared__ float br_s[8][256];
    __shared__ int idxs[8];
    __shared__ int msks[8];
    if (t < 8){
        int tok = tok0 + t;
        idxs[t] = wid[tok];
        msks[t] = ((tok&255) < lens[tok>>8]) ? 1 : 0;
    }
    __syncthreads();
    int f32m = flags[0];
    {
        const float* fp = feat + (size_t)(tok0+tl)*256 + lcol*8;
        f32x4 u0 = *(const f32x4*)fp;
        f32x4 u1 = *(const f32x4*)(fp+4);
        *(f32x4*)&fr_s[tl][lcol*8]   = u0;
        *(f32x4*)&fr_s[tl][lcol*8+4] = u1;
    }
    if (msks[tl]){
        if (f32m){
            const float* bp = (const float*)bank + (size_t)idxs[tl]*256 + lcol*8;
            f32x4 u0 = *(const f32x4*)bp;
            f32x4 u1 = *(const f32x4*)(bp+4);
            *(f32x4*)&br_s[tl][lcol*8]   = u0;
            *(f32x4*)&br_s[tl][lcol*8+4] = u1;
        } else {
            short8 bv = *(const short8*)((const u16*)bank + (size_t)idxs[tl]*256 + lcol*8);
            #pragma unroll
            for (int e=0;e<8;e++) br_s[tl][lcol*8+e] = bf2f((u16)bv[e]);
        }
    } else {
        #pragma unroll
        for (int e=0;e<8;e++) br_s[tl][lcol*8+e] = 0.f;
    }
    __syncthreads();
    float a0 = tagBc[lcol], a1=0.f, a2=0.f, a3=0.f;
    float b0 = memBc[lcol], b1=0.f, b2=0.f, b3=0.f;
    #pragma unroll 4
    for (int cc=0; cc<32; cc++){
        short8 tw = *(const short8*)&tagWT[lcol*256 + cc*8];
        short8 mw = *(const short8*)&memWT[lcol*256 + cc*8];
        f32x4 f0 = *(const f32x4*)&fr_s[tl][cc*8];
        f32x4 f1 = *(const f32x4*)&fr_s[tl][cc*8+4];
        f32x4 g0 = *(const f32x4*)&br_s[tl][cc*8];
        f32x4 g1 = *(const f32x4*)&br_s[tl][cc*8+4];
        a0 = fmaf(f0[0], bf2f((u16)tw[0]), a0);
        a1 = fmaf(f0[1], bf2f((u16)tw[1]), a1);
        a2 = fmaf(f0[2], bf2f((u16)tw[2]), a2);
        a3 = fmaf(f0[3], bf2f((u16)tw[3]), a3);
        a0 = fmaf(f1[0], bf2f((u16)tw[4]), a0);
        a1 = fmaf(f1[1], bf2f((u16)tw[5]), a1);
        a2 = fmaf(f1[2], bf2f((u16)tw[6]), a2);
        a3 = fmaf(f1[3], bf2f((u16)tw[7]), a3);
        b0 = fmaf(g0[0], bf2f((u16)mw[0]), b0);
        b1 = fmaf(g0[1], bf2f((u16)mw[1]), b1);
        b2 = fmaf(g0[2], bf2f((u16)mw[2]), b2);
        b3 = fmaf(g0[3], bf2f((u16)mw[3]), b3);
        b0 = fmaf(g1[0], bf2f((u16)mw[4]), b0);
        b1 = fmaf(g1[1], bf2f((u16)mw[5]), b1);
        b2 = fmaf(g1[2], bf2f((u16)mw[6]), b2);
        b3 = fmaf(g1[3], bf2f((u16)mw[7]), b3);
    }
    float r1 = (a0+a1)+(a2+a3);
    float r2 = (b0+b1)+(b2+b3);
    float res = 0.5f*r1 + 0.5f*r2;
    int tok = tok0 + tl;
    if (f32m) ((float*)out)[(size_t)tok*LL + lcol] = res;
    else      ((u16*)out)[(size_t)tok*LL + lcol]   = f2bf(res);
}

extern "C" void kernel_launch(void* const* d_in, const int* in_sizes, int n_in,
                              void* d_out, int out_size, void* d_ws, size_t ws_size,
                              hipStream_t stream){
    const int* wid  = (const int*)d_in[0];
    const int* lens = (const int*)d_in[1];
    // d_in[2..6]: char_*, mask, idx_inputs — unused (mask recomputed from lens)

    char* ws = (char*)d_ws;
    int*   flags  = (int*)  (ws + 0);
    float* can    = (float*)(ws + 1024);        // 1.74 MB canonical f32 weights
    u16*   WcatT  = (u16*)  (ws + 1900544);     // 1216x128 bf16 = 304 KB
    u16*   tagWT  = (u16*)  (ws + 2211840);     // 16 KB
    u16*   memWT  = (u16*)  (ws + 2228224);     // 16 KB
    float* invn   = (float*)(ws + 2244608);     // 32 KB
    float* cpart  = (float*)(ws + 2277376);     // 128 KB [dir][n][b]
    u16*   weC    = (u16*)  (ws + 4194304);     // 2 MB  [m=s*32+b][128] bf16
    float* lab_e  = (float*)(ws + 8388608);     // 1 MB
    float* sent_h = (float*)(ws + 9437184);     // 4 MB
    float* gpre4  = (float*)(ws + 16777216);    // 32 MiB (pre-scaled f32, K5 layout)
    float* feat   = (float*)(ws + 50331648);    // 8 MB  [b][s][256]

    // canonical sub-offsets (elements)
    float* sentBc = can + 20480;
    float* convWc = can + 20608;
    float* convBc = can + 23680;
    float* Wfc    = can + 23712;
    float* Wbc    = can + 154784;
    float* bfc    = can + 285856;
    float* bbc    = can + 286368;
    float* Ufc    = can + 286880;
    float* Ubc    = can + 352416;
    float* tagBc  = can + 426144;
    float* memBc  = can + 434368;

    static const int cn_n[15]   = {4096,16384,128,3072,32,131072,131072,512,512,65536,65536,8192,32,8192,32};
    static const int cn_src[15] = {8,9,10,11,12,13,16,15,18,14,17,19,20,21,22};
    PJobs jb;
    int nblk = 0;
    {
        int off = 0;
        for (int i=0;i<15;i++){
            jb.src[i]=d_in[cn_src[i]]; jb.n[i]=cn_n[i]; jb.p0[i]=off; jb.p1[i]=0; jb.type[i]=0;
            off+=cn_n[i];
        }
        jb.src[15]=d_in[13]; jb.n[15]=65536;  jb.p0[15]=0;    jb.p1[15]=512; jb.type[15]=4; // Wf q-perm
        jb.src[16]=d_in[16]; jb.n[16]=65536;  jb.p0[16]=512;  jb.p1[16]=512; jb.type[16]=4; // Wb q-perm
        jb.src[17]=d_in[9];  jb.n[17]=16384;  jb.p0[17]=1024; jb.p1[17]=128; jb.type[17]=1; // sentW
        jb.src[18]=d_in[19]; jb.n[18]=8192;   jb.p0[18]=0;    jb.p1[18]=0;   jb.type[18]=2;
        jb.src[19]=d_in[21]; jb.n[19]=8192;   jb.p0[19]=1;    jb.p1[19]=0;   jb.type[19]=2;
        jb.src[20]=d_in[8];  jb.n[20]=4096;   jb.p0[20]=0;    jb.p1[20]=0;   jb.type[20]=3; // label norm
        jb.src[21]=d_in[7];  jb.n[21]=262144; jb.p0[21]=0;    jb.p1[21]=0;   jb.type[21]=5; // token gather
        for (int i=0;i<NJOBS;i++){ jb.blk0[i] = nblk; nblk += (jb.n[i] + 255)/256; }
    }

    kprep  <<<nblk, 256, 0, stream>>>(jb, d_in[7], wid, flags, can, WcatT, tagWT, memWT,
                                      weC, invn);
    kgemm  <<<dim3(128,19), 256, 0, stream>>>(weC, WcatT, invn, sentBc, gpre4, sent_h, lab_e);
    k23f   <<<32, 256, 0, stream>>>(lab_e, convWc, convBc, sent_h, lens,
                                    Wfc, Wbc, bfc, bbc, cpart);
    k5_lstm<<<16, 512, 0, stream>>>(gpre4, Ufc, Ubc, cpart, lens, feat);
    k6_final<<<1024, 256, 0, stream>>>(feat, wid, lens, tagWT, tagBc, memWT, memBc,
                                       d_in[23], flags, d_out);
}

// Round 14
// 207.018 us; speedup vs baseline: 1.7100x; 1.7100x over previous
//
#include <hip/hip_runtime.h>
#include <hip/hip_bf16.h>

#define BB 32
#define SS 256
#define DD 128
#define GG 128
#define NG 512   // 4*(H/2) gate columns per direction
#define LL 32
#define LOG2E 1.4426950408889634f

typedef unsigned short u16;
typedef __attribute__((ext_vector_type(8))) short short8;
typedef __attribute__((ext_vector_type(4))) float f32x4;

__device__ __forceinline__ float bf2f(u16 u){ return __uint_as_float(((unsigned)u)<<16); }
__device__ __forceinline__ u16 f2bf(float f){
    unsigned x = __float_as_uint(f);
    unsigned r = x + 0x7fffu + ((x>>16)&1u);
    return (u16)(r>>16);
}
__device__ __forceinline__ float tanh_f(float x){ float e=__expf(2.0f*x); return 1.0f - 2.0f/(e+1.0f); }

__device__ __forceinline__ float exp2_f(float x){
#if __has_builtin(__builtin_amdgcn_exp2f)
    return __builtin_amdgcn_exp2f(x);
#elif __has_builtin(__builtin_amdgcn_expf)
    return __builtin_amdgcn_expf(x);
#else
    return __expf(x * 0.6931471805599453f);
#endif
}
__device__ __forceinline__ float rcp_f(float x){
#if __has_builtin(__builtin_amdgcn_rcpf)
    return __builtin_amdgcn_rcpf(x);
#else
    return 1.0f / x;
#endif
}

// ---------------- kprep: flat job table (exact block ranges) ----------------
// type 0: can[p0+i] = f32(src[i])
// type 1: WcatT[(p0 + c)*128 + k] = bf16(src[k*p1 + c])            (plain W^T)
// type 2: (p0? memWT : tagWT)[(i&31)*256 + (i>>5)] = bf16(...)
// type 3: label row-norm -> WcatT cols 1152..1183 (+ zero pad)
// type 4: gate W^T with q-permute
// type 5: token gather+norm -> weC(bf16), invn
#define NJOBS 22
struct PJobs { const void* src[NJOBS]; int n[NJOBS]; int p0[NJOBS]; int p1[NJOBS];
               int type[NJOBS]; int blk0[NJOBS]; };

__global__ void kprep(PJobs jb, const void* __restrict__ wemb, const int* __restrict__ wid,
                      int* __restrict__ flags, float* __restrict__ can,
                      u16* __restrict__ WcatT, u16* __restrict__ tagWT, u16* __restrict__ memWT,
                      u16* __restrict__ weC, float* __restrict__ invn){
    int t = threadIdx.x;
    __shared__ int cw[4];
    __shared__ int sflag;
    {
        u16 v = ((const u16*)wemb)[2*t];
        int e = (v>>7)&0xFF;
        int c = (e>=0x90)?1:0;
        #pragma unroll
        for (int mk=32; mk>0; mk>>=1) c += __shfl_xor(c, mk);
        if ((t&63)==0) cw[t>>6] = c;
        __syncthreads();
        if (t==0) sflag = (cw[0]+cw[1]+cw[2]+cw[3] >= 32) ? 1 : 0;
        __syncthreads();
    }
    int f = sflag;
    if (blockIdx.x==0 && t==0) flags[0] = f;

    int bx = blockIdx.x;
    int id = 0;
    #pragma unroll
    for (int jj=1; jj<NJOBS; jj++) if (bx >= jb.blk0[jj]) id = jj;
    int i = (bx - jb.blk0[id])*256 + t;
    if (i >= jb.n[id]) return;
    const void* src = jb.src[id];
    int p0 = jb.p0[id];
    int ty = jb.type[id];
    if (ty == 0){
        float v = f ? ((const float*)src)[i] : bf2f(((const u16*)src)[i]);
        can[p0 + i] = v;
    } else if (ty == 1){
        int c = i>>7, k = i&127;
        float v = f ? ((const float*)src)[k*jb.p1[id] + c] : bf2f(((const u16*)src)[k*jb.p1[id] + c]);
        WcatT[(size_t)(p0 + c)*128 + k] = f2bf(v);
    } else if (ty == 2){
        int l = i&31, k = i>>5;
        float v = f ? ((const float*)src)[k*32 + l] : bf2f(((const u16*)src)[k*32 + l]);
        (p0 ? memWT : tagWT)[l*256 + k] = f2bf(v);
    } else if (ty == 3){
        int row = i>>7, col = i&127;
        float v = f ? ((const float*)src)[i] : bf2f(((const u16*)src)[i]);
        float sq = v*v;
        #pragma unroll
        for (int mk=32; mk>0; mk>>=1) sq += __shfl_xor(sq, mk);
        __shared__ float r4[4];
        if ((t&63)==0) r4[t>>6] = sq;
        __syncthreads();
        int half = t>>7;
        float tot = r4[half*2] + r4[half*2+1];
        float inv = 1.0f/(sqrtf(tot) + 1e-8f);
        WcatT[(size_t)(1152+row)*128 + col] = f2bf(v*inv);
        WcatT[(size_t)(1184+row)*128 + col] = 0;   // pad cols
    } else if (ty == 4){
        int c = i>>7, k = i&127;
        float v = f ? ((const float*)src)[k*512 + c] : bf2f(((const u16*)src)[k*512 + c]);
        int q = c>>7, rem = c&127, w5 = rem>>4, li = rem&15;
        WcatT[(size_t)(p0 + w5*64 + q*16 + li)*128 + k] = f2bf(v);
    } else {
        // type 5: token gather + norm (8 tokens per block, 32 lanes each)
        int tok = i>>5, lane = i&31;
        int idx = wid[tok];
        float v0,v1,v2,v3;
        if (f){
            f32x4 u = *(const f32x4*)((const float*)wemb + (size_t)idx*DD + lane*4);
            v0=u[0]; v1=u[1]; v2=u[2]; v3=u[3];
        } else {
            ushort4 u = *(const ushort4*)((const u16*)wemb + (size_t)idx*DD + lane*4);
            v0=bf2f(u.x); v1=bf2f(u.y); v2=bf2f(u.z); v3=bf2f(u.w);
        }
        int b = tok>>8, s = tok&255;
        int m = s*BB + b;
        ushort4 wv;
        wv.x=f2bf(v0); wv.y=f2bf(v1); wv.z=f2bf(v2); wv.w=f2bf(v3);
        *(ushort4*)&weC[(size_t)m*DD + lane*4] = wv;
        float sq = v0*v0 + v1*v1 + v2*v2 + v3*v3;
        #pragma unroll
        for (int mk=16; mk>0; mk>>=1) sq += __shfl_xor(sq, mk);
        if (lane==0) invn[m] = 1.0f/(sqrtf(sq) + 1e-8f);
    }
}

// ---------------- kgemm: [gpre4(f32) | sent_h | lab_e] = weC @ WcatT, MFMA ----------------
// nb<16: (dir = nb>>3, w5 = nb&7), q-permuted cols -> f32x4-coalesced gpre4 stores.
__global__ __launch_bounds__(256) void kgemm(const u16* __restrict__ weC,
                      const u16* __restrict__ WcatT,
                      const float* __restrict__ invn, const float* __restrict__ sentBc,
                      float* __restrict__ gpre4, float* __restrict__ sent_h,
                      float* __restrict__ lab_e){
    int mt = blockIdx.x;            // 0..127
    int nb = blockIdx.y;            // 0..18
    int t = threadIdx.x;
    int w4 = t>>6, l = t&63, li = l&15, lg = l>>4;
    int mbase = mt*64 + w4*16;
    int n0 = nb*64;
    short8 af[4];
    #pragma unroll
    for (int ks=0;ks<4;ks++)
        af[ks] = *(const short8*)&weC[(size_t)(mbase + li)*128 + ks*32 + lg*8];
    f32x4 acc[4];
    #pragma unroll
    for (int nt=0;nt<4;nt++){
        short8 bf[4];
        #pragma unroll
        for (int ks=0;ks<4;ks++)
            bf[ks] = *(const short8*)&WcatT[(size_t)(n0 + nt*16 + li)*128 + ks*32 + lg*8];
        f32x4 a; a[0]=0.f; a[1]=0.f; a[2]=0.f; a[3]=0.f;
        #pragma unroll
        for (int ks=0;ks<4;ks++)
            a = __builtin_amdgcn_mfma_f32_16x16x32_bf16(af[ks], bf[ks], a, 0,0,0);
        acc[nt] = a;
    }
    if (nb < 16){
        int dir = nb>>3, w5 = nb&7;
        int s = mt*2 + (w4>>1);
        int bg = (w4&1)*4 + lg;
        float* gp = gpre4 + ((((size_t)(dir*8+bg)*256 + s)*8 + w5)*256);
        #pragma unroll
        for (int r=0;r<4;r++){
            f32x4 v;
            v[0] = acc[0][r]*LOG2E;
            v[1] = acc[1][r]*LOG2E;
            v[2] = acc[2][r]*(2.0f*LOG2E);
            v[3] = acc[3][r]*LOG2E;
            *(f32x4*)&gp[(r*16 + li)*4] = v;
        }
    } else {
        int mrow = mbase + lg*4;
        #pragma unroll
        for (int nt=0;nt<4;nt++){
            int n = n0 + nt*16 + li;
            if (n < 1152){
                int c = n - 1024;
                float bb = sentBc[c];
                #pragma unroll
                for (int r=0;r<4;r++){
                    int m = mrow + r;
                    int b = m&31, s = m>>5;
                    sent_h[((size_t)(b*256+s))*128 + c] = tanh_f(acc[nt][r] + bb);
                }
            } else if (n < 1184){
                int c = n - 1152;
                #pragma unroll
                for (int r=0;r<4;r++){
                    int m = mrow + r;
                    int b = m&31, s = m>>5;
                    lab_e[((size_t)(b*256+s))*32 + c] = acc[nt][r] * invn[m];
                }
            }
        }
    }
}

// ---------------- k23p: conv+relu+max+exp fused with partial attention sums ----------------
__global__ __launch_bounds__(256) void k23p(const float* __restrict__ lab_e,
                        const float* __restrict__ convWc, const float* __restrict__ convBc,
                        const float* __restrict__ sent_h,
                        const int* __restrict__ lens,
                        float* __restrict__ srp, float* __restrict__ esum_p){
    int b = blockIdx.x, stile = blockIdx.y, t = threadIdx.x;
    int sl = t>>3, oq = t&7;
    int s = stile*32 + sl;
    __shared__ float le_s[34*33];
    __shared__ float wle[LL*LL*3];
    __shared__ float wb[LL];
    __shared__ float es[32];
    __shared__ float red[2][GG];
    int s0 = stile*32;
    for (int i=t; i<34*32; i+=256){
        int row = i>>5, col = i&31;
        int sg = s0 - 1 + row;
        le_s[row*33 + col] = (sg>=0 && sg<SS) ? lab_e[(size_t)b*SS*LL + sg*LL + col] : 0.f;
    }
    for (int i=t; i<LL*LL*3; i+=256) wle[i] = convWc[i];
    if (t < LL) wb[t] = convBc[t];
    __syncthreads();
    float lm = 0.f;   // relu >= 0
    #pragma unroll
    for (int op=0; op<4; op++){
        int o = oq*4 + op;
        float a0 = wb[o], a1 = 0.f, a2 = 0.f;
        #pragma unroll
        for (int i=0;i<LL;i++){
            a0 = fmaf(le_s[(sl+0)*33+i], wle[o*96 + i*3    ], a0);
            a1 = fmaf(le_s[(sl+1)*33+i], wle[o*96 + i*3 + 1], a1);
            a2 = fmaf(le_s[(sl+2)*33+i], wle[o*96 + i*3 + 2], a2);
        }
        lm = fmaxf(lm, fmaxf(a0+a1+a2, 0.f));
    }
    #pragma unroll
    for (int mk=1; mk<8; mk<<=1) lm = fmaxf(lm, __shfl_xor(lm, mk));
    if (oq == 0) es[sl] = (s < lens[b]) ? __expf(lm) : 0.f;
    __syncthreads();
    int col = t&127, sh = t>>7;
    float a0 = 0.f, a1 = 0.f;
    int sb = s0 + sh*16;
    #pragma unroll
    for (int s2=0; s2<16; s2+=2){
        a0 = fmaf(es[sh*16+s2],   sent_h[((size_t)b*SS + sb+s2)*GG + col], a0);
        a1 = fmaf(es[sh*16+s2+1], sent_h[((size_t)b*SS + sb+s2+1)*GG + col], a1);
    }
    red[sh][col] = a0+a1;
    __syncthreads();
    if (t < GG) srp[((size_t)b*8 + stile)*GG + t] = red[0][t] + red[1][t];
    if (t < 32){
        float e = es[t];
        #pragma unroll
        for (int mk=16; mk>0; mk>>=1) e += __shfl_xor(e, mk);
        if (t==0) esum_p[b*8 + stile] = e;
    }
}

// ---------------- k3b: combine partials + cpart matvec ----------------
__global__ void k3b_cpart(const float* __restrict__ srp, const float* __restrict__ esum_p,
                          const float* __restrict__ Wfc, const float* __restrict__ Wbc,
                          const float* __restrict__ bfc, const float* __restrict__ bbc,
                          float* __restrict__ cpart){
    int chunk = blockIdx.x, b = blockIdx.y, t = threadIdx.x;  // 4 x 32, 256 thr
    __shared__ float srs[GG];
    if (t < GG){
        float a = 0.f;
        #pragma unroll
        for (int st=0; st<8; st++) a += srp[((size_t)b*8 + st)*GG + t];
        float es = 0.f;
        #pragma unroll
        for (int st=0; st<8; st++) es += esum_p[b*8 + st];
        srs[t] = a * (1.0f/es);
    }
    __syncthreads();
    int ng = chunk*256 + t;          // 0..1023
    int dir = ng>>9, n = ng&511;
    const float* W = dir ? Wbc : Wfc;
    float c0 = (dir ? bbc : bfc)[n], c1 = 0.f;
    for (int g=0; g<GG; g+=2){
        c0 = fmaf(srs[g],   W[(size_t)(DD+g)*NG + n], c0);
        c1 = fmaf(srs[g+1], W[(size_t)(DD+g+1)*NG + n], c1);
    }
    cpart[((size_t)dir*NG + n)*BB + b] = c0+c1;
}

// ---------------- K5: bidir LSTM, 16 wgs, 1 cell/lane, predicated A-read (frozen R10 form) ----------------
__global__ __launch_bounds__(512) void k5_lstm(const float* __restrict__ gpre4,
                       const float* __restrict__ Ufc, const float* __restrict__ Ubc,
                       const float* __restrict__ cpart,
                       const int* __restrict__ lens, float* __restrict__ feat){
    int dir = blockIdx.x>>3, bg = blockIdx.x&7;
    int t = threadIdx.x;
    int w = t>>6, l = t&63, lg = l>>4, li = l&15;
    int j = w*16 + li;                         // hidden column 0..127
    int b = bg*4 + lg;                         // this lane's batch
    const float* Uc = dir ? Ubc : Ufc;

    short8 bfr[4][4];
    #pragma unroll
    for (int q=0;q<4;q++){
        float sc = (q==2) ? 2.0f*LOG2E : LOG2E;
        #pragma unroll
        for (int ks=0;ks<4;ks++){
            int n = q*128 + j;
            short8 v;
            #pragma unroll
            for (int jj=0;jj<8;jj++)
                v[jj] = (short)f2bf(Uc[(size_t)(ks*32 + lg*8 + jj)*NG + n] * sc);
            bfr[q][ks] = v;
        }
    }
    float cpr[4];
    #pragma unroll
    for (int q=0;q<4;q++)
        cpr[q] = cpart[((size_t)(dir*NG + q*128 + j))*BB + b] * ((q==2) ? 2.0f*LOG2E : LOG2E);
    int len1 = lens[b];

    __shared__ u16 Hhi[2][16*128];   // XOR-swizzled, double-buffered
    for (int i=t; i<2*2048; i+=512) ((u16*)Hhi)[i] = 0;

    bool rdp = ((li & 3) == 0);      // only 16 lanes/wave read the A tile
    int roff[4];
    #pragma unroll
    for (int ks=0;ks<4;ks++)
        roff[ks] = (li*256 + ((ks*64 + lg*16) ^ ((li&7)<<4))) >> 1;
    int woff;
    { int row = lg*4; woff = (row*256 + ((2*j) ^ ((row&7)<<4))) >> 1; }

    short8 ah[4];
    #pragma unroll
    for (int ks=0;ks<4;ks++){
        #pragma unroll
        for (int jj=0;jj<8;jj++) ah[ks][jj] = 0;
    }
    f32x4 acv[4];
    #pragma unroll
    for (int q=0;q<4;q++){ acv[q][0]=0.f; acv[q][1]=0.f; acv[q][2]=0.f; acv[q][3]=0.f; }

    float c = 0.f, h = 0.f;
    int sgn = dir ? -1 : 1;
    int s0 = dir ? (SS-1) : 0;
    const float* gl = gpre4 + ((size_t)(dir*8 + bg)*256 + s0)*2048 + w*256 + l*4;
    ptrdiff_t gstep = (ptrdiff_t)sgn * 2048;

    f32x4 gA = *(const f32x4*)gl;
    f32x4 gB = *(const f32x4*)(gl + gstep);
    const float* glp = gl + 2*gstep;

    float* fb = feat + ((size_t)b*SS + s0)*256 + dir*128 + j;
    ptrdiff_t fstep = (ptrdiff_t)sgn * 256;

    int s = s0;
    __syncthreads();

#define K5_STEP(P, G)                                                          \
    {                                                                          \
        if (rdp){                                                              \
            ah[0] = *(const short8*)&Hhi[P][roff[0]];                          \
            ah[1] = *(const short8*)&Hhi[P][roff[1]];                          \
            ah[2] = *(const short8*)&Hhi[P][roff[2]];                          \
            ah[3] = *(const short8*)&Hhi[P][roff[3]];                          \
        }                                                                      \
        acv[0][0] = G[0]+cpr[0];                                               \
        acv[1][0] = G[1]+cpr[1];                                               \
        acv[2][0] = G[2]+cpr[2];                                               \
        acv[3][0] = G[3]+cpr[3];                                               \
        if (tt2 + 2 < SS){ G = *(const f32x4*)glp; glp += gstep; }             \
        _Pragma("unroll")                                                      \
        for (int ks=0;ks<4;ks++){                                              \
            _Pragma("unroll")                                                  \
            for (int q=0;q<4;q++)                                              \
                acv[q] = __builtin_amdgcn_mfma_f32_16x16x32_bf16(ah[ks], bfr[q][ks], acv[q], 0,0,0); \
        }                                                                      \
        float si = rcp_f(1.0f + exp2_f(-acv[0][0]));                           \
        float sf = rcp_f(1.0f + exp2_f(-acv[1][0]));                           \
        float tg = 1.0f - 2.0f*rcp_f(exp2_f(acv[2][0]) + 1.0f);                \
        float so = rcp_f(1.0f + exp2_f(-acv[3][0]));                           \
        float cn = sf*c + si*tg;                                               \
        float th = 1.0f - 2.0f*rcp_f(exp2_f(cn*(2.0f*LOG2E)) + 1.0f);          \
        float hn = so*th;                                                      \
        if (s < 128){ c = cn; h = hn; fb[0] = hn; }                            \
        else { bool mm = (s < len1); c = mm?cn:c; h = mm?hn:h; fb[0] = mm?hn:0.f; } \
        Hhi[P^1][woff] = f2bf(h);                                              \
        asm volatile("s_waitcnt lgkmcnt(0)" ::: "memory");                     \
        __builtin_amdgcn_sched_barrier(0);                                     \
        __builtin_amdgcn_s_barrier();                                          \
        __builtin_amdgcn_sched_barrier(0);                                     \
        s += sgn; fb += fstep;                                                 \
    }

    for (int tt=0; tt<SS; tt+=2){
        { int tt2 = tt;   K5_STEP(0, gA) }
        { int tt2 = tt+1; K5_STEP(1, gB) }
    }
#undef K5_STEP
}

// ---------------- k6: tag/mem projections + blend (LDS-staged, vectorized) ----------------
__global__ __launch_bounds__(256) void k6_final(const float* __restrict__ feat,
                         const int* __restrict__ wid,
                         const int* __restrict__ lens,
                         const u16* __restrict__ tagWT, const float* __restrict__ tagBc,
                         const u16* __restrict__ memWT, const float* __restrict__ memBc,
                         const void* __restrict__ bank, const int* __restrict__ flags,
                         void* __restrict__ out){
    int t = threadIdx.x;
    int tl = t>>5, lcol = t&31;
    int tok0 = blockIdx.x*8;
    __shared__ float fr_s[8][256];
    __shared__ float br_s[8][256];
    __shared__ int idxs[8];
    __shared__ int msks[8];
    if (t < 8){
        int tok = tok0 + t;
        idxs[t] = wid[tok];
        msks[t] = ((tok&255) < lens[tok>>8]) ? 1 : 0;
    }
    __syncthreads();
    int f32m = flags[0];
    {
        const float* fp = feat + (size_t)(tok0+tl)*256 + lcol*8;
        f32x4 u0 = *(const f32x4*)fp;
        f32x4 u1 = *(const f32x4*)(fp+4);
        *(f32x4*)&fr_s[tl][lcol*8]   = u0;
        *(f32x4*)&fr_s[tl][lcol*8+4] = u1;
    }
    if (msks[tl]){
        if (f32m){
            const float* bp = (const float*)bank + (size_t)idxs[tl]*256 + lcol*8;
            f32x4 u0 = *(const f32x4*)bp;
            f32x4 u1 = *(const f32x4*)(bp+4);
            *(f32x4*)&br_s[tl][lcol*8]   = u0;
            *(f32x4*)&br_s[tl][lcol*8+4] = u1;
        } else {
            short8 bv = *(const short8*)((const u16*)bank + (size_t)idxs[tl]*256 + lcol*8);
            #pragma unroll
            for (int e=0;e<8;e++) br_s[tl][lcol*8+e] = bf2f((u16)bv[e]);
        }
    } else {
        #pragma unroll
        for (int e=0;e<8;e++) br_s[tl][lcol*8+e] = 0.f;
    }
    __syncthreads();
    float a0 = tagBc[lcol], a1=0.f, a2=0.f, a3=0.f;
    float b0 = memBc[lcol], b1=0.f, b2=0.f, b3=0.f;
    #pragma unroll 4
    for (int cc=0; cc<32; cc++){
        short8 tw = *(const short8*)&tagWT[lcol*256 + cc*8];
        short8 mw = *(const short8*)&memWT[lcol*256 + cc*8];
        f32x4 f0 = *(const f32x4*)&fr_s[tl][cc*8];
        f32x4 f1 = *(const f32x4*)&fr_s[tl][cc*8+4];
        f32x4 g0 = *(const f32x4*)&br_s[tl][cc*8];
        f32x4 g1 = *(const f32x4*)&br_s[tl][cc*8+4];
        a0 = fmaf(f0[0], bf2f((u16)tw[0]), a0);
        a1 = fmaf(f0[1], bf2f((u16)tw[1]), a1);
        a2 = fmaf(f0[2], bf2f((u16)tw[2]), a2);
        a3 = fmaf(f0[3], bf2f((u16)tw[3]), a3);
        a0 = fmaf(f1[0], bf2f((u16)tw[4]), a0);
        a1 = fmaf(f1[1], bf2f((u16)tw[5]), a1);
        a2 = fmaf(f1[2], bf2f((u16)tw[6]), a2);
        a3 = fmaf(f1[3], bf2f((u16)tw[7]), a3);
        b0 = fmaf(g0[0], bf2f((u16)mw[0]), b0);
        b1 = fmaf(g0[1], bf2f((u16)mw[1]), b1);
        b2 = fmaf(g0[2], bf2f((u16)mw[2]), b2);
        b3 = fmaf(g0[3], bf2f((u16)mw[3]), b3);
        b0 = fmaf(g1[0], bf2f((u16)mw[4]), b0);
        b1 = fmaf(g1[1], bf2f((u16)mw[5]), b1);
        b2 = fmaf(g1[2], bf2f((u16)mw[6]), b2);
        b3 = fmaf(g1[3], bf2f((u16)mw[7]), b3);
    }
    float r1 = (a0+a1)+(a2+a3);
    float r2 = (b0+b1)+(b2+b3);
    float res = 0.5f*r1 + 0.5f*r2;
    int tok = tok0 + tl;
    if (f32m) ((float*)out)[(size_t)tok*LL + lcol] = res;
    else      ((u16*)out)[(size_t)tok*LL + lcol]   = f2bf(res);
}

extern "C" void kernel_launch(void* const* d_in, const int* in_sizes, int n_in,
                              void* d_out, int out_size, void* d_ws, size_t ws_size,
                              hipStream_t stream){
    const int* wid  = (const int*)d_in[0];
    const int* lens = (const int*)d_in[1];
    // d_in[2..6]: char_*, mask, idx_inputs — unused (mask recomputed from lens)

    char* ws = (char*)d_ws;
    int*   flags  = (int*)  (ws + 0);
    float* can    = (float*)(ws + 1024);        // 1.74 MB canonical f32 weights
    u16*   WcatT  = (u16*)  (ws + 1900544);     // 1216x128 bf16 = 304 KB
    u16*   tagWT  = (u16*)  (ws + 2211840);     // 16 KB
    u16*   memWT  = (u16*)  (ws + 2228224);     // 16 KB
    float* invn   = (float*)(ws + 2244608);     // 32 KB
    float* cpart  = (float*)(ws + 2277376);     // 128 KB [dir][n][b]
    float* srp    = (float*)(ws + 2441216);     // 128 KB [b][8][128] partials
    float* esum_p = (float*)(ws + 2572288);     // 1 KB
    u16*   weC    = (u16*)  (ws + 4194304);     // 2 MB  [m=s*32+b][128] bf16
    float* lab_e  = (float*)(ws + 8388608);     // 1 MB
    float* sent_h = (float*)(ws + 9437184);     // 4 MB
    float* gpre4  = (float*)(ws + 16777216);    // 32 MiB (pre-scaled f32, K5 layout)
    float* feat   = (float*)(ws + 50331648);    // 8 MB  [b][s][256]

    // canonical sub-offsets (elements)
    float* sentBc = can + 20480;
    float* convWc = can + 20608;
    float* convBc = can + 23680;
    float* Wfc    = can + 23712;
    float* Wbc    = can + 154784;
    float* bfc    = can + 285856;
    float* bbc    = can + 286368;
    float* Ufc    = can + 286880;
    float* Ubc    = can + 352416;
    float* tagBc  = can + 426144;
    float* memBc  = can + 434368;

    static const int cn_n[15]   = {4096,16384,128,3072,32,131072,131072,512,512,65536,65536,8192,32,8192,32};
    static const int cn_src[15] = {8,9,10,11,12,13,16,15,18,14,17,19,20,21,22};
    PJobs jb;
    int nblk = 0;
    {
        int off = 0;
        for (int i=0;i<15;i++){
            jb.src[i]=d_in[cn_src[i]]; jb.n[i]=cn_n[i]; jb.p0[i]=off; jb.p1[i]=0; jb.type[i]=0;
            off+=cn_n[i];
        }
        jb.src[15]=d_in[13]; jb.n[15]=65536;  jb.p0[15]=0;    jb.p1[15]=512; jb.type[15]=4; // Wf q-perm
        jb.src[16]=d_in[16]; jb.n[16]=65536;  jb.p0[16]=512;  jb.p1[16]=512; jb.type[16]=4; // Wb q-perm
        jb.src[17]=d_in[9];  jb.n[17]=16384;  jb.p0[17]=1024; jb.p1[17]=128; jb.type[17]=1; // sentW
        jb.src[18]=d_in[19]; jb.n[18]=8192;   jb.p0[18]=0;    jb.p1[18]=0;   jb.type[18]=2;
        jb.src[19]=d_in[21]; jb.n[19]=8192;   jb.p0[19]=1;    jb.p1[19]=0;   jb.type[19]=2;
        jb.src[20]=d_in[8];  jb.n[20]=4096;   jb.p0[20]=0;    jb.p1[20]=0;   jb.type[20]=3; // label norm
        jb.src[21]=d_in[7];  jb.n[21]=262144; jb.p0[21]=0;    jb.p1[21]=0;   jb.type[21]=5; // token gather
        for (int i=0;i<NJOBS;i++){ jb.blk0[i] = nblk; nblk += (jb.n[i] + 255)/256; }
    }

    kprep  <<<nblk, 256, 0, stream>>>(jb, d_in[7], wid, flags, can, WcatT, tagWT, memWT,
                                      weC, invn);
    kgemm  <<<dim3(128,19), 256, 0, stream>>>(weC, WcatT, invn, sentBc, gpre4, sent_h, lab_e);
    k23p   <<<dim3(32,8), 256, 0, stream>>>(lab_e, convWc, convBc, sent_h, lens, srp, esum_p);
    k3b_cpart<<<dim3(4,32), 256, 0, stream>>>(srp, esum_p, Wfc, Wbc, bfc, bbc, cpart);
    k5_lstm<<<16, 512, 0, stream>>>(gpre4, Ufc, Ubc, cpart, lens, feat);
    k6_final<<<1024, 256, 0, stream>>>(feat, wid, lens, tagWT, tagBc, memWT, memBc,
                                       d_in[23], flags, d_out);
}